// Round 5
// baseline (590.828 us; speedup 1.0000x reference)
//
#include <hip/hip_runtime.h>
#include <hip/hip_bf16.h>
#include <stdint.h>

typedef __bf16 bf16;
typedef bf16 bf16x8 __attribute__((ext_vector_type(8)));
typedef bf16 bf16x4 __attribute__((ext_vector_type(4)));
typedef float f32x4 __attribute__((ext_vector_type(4)));

constexpr int N = 2048;   // tokens
constexpr int C = 1024;   // model dim
constexpr int H = 2048;   // hidden dim
constexpr int E = 8;      // experts
constexpr float EPS = 1.1920929e-07f;

constexpr int BM = 64, BN = 64, BK = 32;   // 64x64 tile, triple-buffered K-loop
constexpr int BUF = BM * BK * 2;           // 4096 B per LDS buffer
constexpr int GT = 32;                     // tokens per gate block

#define GPTR(p) (__attribute__((address_space(1))) void*)(p)
#define LPTR(p) (__attribute__((address_space(3))) void*)(p)
// fine-grained waits: leave prefetch loads in flight across the barrier
#define WAIT_VM2() asm volatile("s_waitcnt vmcnt(2)" ::: "memory")
#define WAIT_VM0() asm volatile("s_waitcnt vmcnt(0)" ::: "memory")

// ---------------------------------------------------------------- small init
__global__ void init_kernel(int* counts, float* scoresums) {
  int t = threadIdx.x;
  if (t < E) counts[t] = 0;
  if (t < E) scoresums[t] = 0.f;
}

// ------------------------------------------------- fp32 -> bf16 cvt (merged)
__global__ void cvt_all_kernel(const float* __restrict__ w1, const float* __restrict__ w2,
                               const float* __restrict__ kw, const float* __restrict__ vw,
                               bf16* __restrict__ w1b, bf16* __restrict__ w2b,
                               bf16* __restrict__ kwb, bf16* __restrict__ vwb) {
  size_t i = (size_t)blockIdx.x * 256 + threadIdx.x;     // float4 units
  const size_t n1 = (size_t)E * H * C / 4;
  const size_t n2 = n1 * 2;
  const size_t n3 = n2 + (size_t)H * C / 4;
  const float4* src; bf16x4* dst; size_t off;
  if (i < n1)      { src = (const float4*)w1; dst = (bf16x4*)w1b; off = i; }
  else if (i < n2) { src = (const float4*)w2; dst = (bf16x4*)w2b; off = i - n1; }
  else if (i < n3) { src = (const float4*)kw; dst = (bf16x4*)kwb; off = i - n2; }
  else             { src = (const float4*)vw; dst = (bf16x4*)vwb; off = i - n3; }
  float4 v = src[off];
  bf16x4 o = { (bf16)v.x, (bf16)v.y, (bf16)v.z, (bf16)v.w };
  dst[off] = o;
}

// --------------------------------------------------------------- rmsnorm(x)
__global__ void rmsnorm_kernel(const float* __restrict__ x,
                               bf16* __restrict__ xtb,
                               float* __restrict__ rs1_arr,
                               float* __restrict__ rs2_arr) {
  int n = blockIdx.x;
  int tid = threadIdx.x;                      // 256 threads, 1 float4 each
  float4 v = ((const float4*)(x + (size_t)n * C))[tid];
  float ss = v.x*v.x + v.y*v.y + v.z*v.z + v.w*v.w;
  #pragma unroll
  for (int off = 32; off > 0; off >>= 1) ss += __shfl_down(ss, off, 64);
  __shared__ float red[4];
  __shared__ float tot;
  int wave = tid >> 6, lane = tid & 63;
  if (lane == 0) red[wave] = ss;
  __syncthreads();
  if (tid == 0) tot = red[0] + red[1] + red[2] + red[3];
  __syncthreads();
  float sumsq = tot;
  float rs1 = rsqrtf(sumsq * (1.f / C) + EPS);
  bf16x4 o = { (bf16)(v.x*rs1), (bf16)(v.y*rs1), (bf16)(v.z*rs1), (bf16)(v.w*rs1) };
  ((bf16x4*)(xtb + (size_t)n * C))[tid] = o;
  if (tid == 0) {
    rs1_arr[n] = rs1;
    float m2 = sumsq * rs1 * rs1 * (1.f / C);  // mean(xt^2) exactly
    rs2_arr[n] = rsqrtf(m2 + EPS);
  }
}

// ------------------------------------------------------------------- gating
__global__ __launch_bounds__(256) void gate_kernel(
    const float* __restrict__ x, const float* __restrict__ rs1_arr,
    const float* __restrict__ gate_w, const float* __restrict__ sgw,
    float* __restrict__ g, float* __restrict__ sgbuf,
    int* __restrict__ counts, int* __restrict__ lists,
    float* __restrict__ scoresums) {
  __shared__ float wsm[9][1024];   // 36 KB: 8 expert rows + shared-gate row
  __shared__ float s_scores[8];
  __shared__ int   s_cnt[8];
  __shared__ int   s_base[8];
  __shared__ int   s_e1[GT], s_p1[GT], s_e2[GT], s_p2[GT];
  const int tid = threadIdx.x, lane = tid & 63, wave = tid >> 6;
  for (int i = tid; i < 9 * 1024; i += 256) {
    int e = i >> 10, c = i & 1023;
    wsm[e][c] = (e < 8) ? gate_w[i] : sgw[c];
  }
  if (tid < 8) { s_scores[tid] = 0.f; s_cnt[tid] = 0; }
  __syncthreads();

  const int tok0 = blockIdx.x * GT + wave * (GT / 4);
  for (int tt = 0; tt < GT / 4; ++tt) {
    const int tok = tok0 + tt;
    const float* xr = x + (size_t)tok * C;
    float acc[9];
    #pragma unroll
    for (int e = 0; e < 9; e++) acc[e] = 0.f;
    #pragma unroll
    for (int k = 0; k < 16; ++k) {
      int c = k * 64 + lane;
      float xv = xr[c];
      #pragma unroll
      for (int e = 0; e < 9; e++) acc[e] = fmaf(xv, wsm[e][c], acc[e]);
    }
    #pragma unroll
    for (int e = 0; e < 9; e++) {
      float v = acc[e];
      #pragma unroll
      for (int off = 32; off > 0; off >>= 1) v += __shfl_xor(v, off, 64);
      acc[e] = v;
    }
    if (lane == 0) {
      float rs1 = rs1_arr[tok];
      float raw[9];
      #pragma unroll
      for (int e = 0; e < 9; e++) raw[e] = acc[e] * rs1;
      float m = raw[0];
      for (int e = 1; e < 8; e++) m = fmaxf(m, raw[e]);
      float sc[8], s = 0.f;
      for (int e = 0; e < 8; e++) { sc[e] = expf(raw[e] - m); s += sc[e]; }
      float inv = 1.f / s;
      for (int e = 0; e < 8; e++) sc[e] *= inv;
      int i1 = 0;
      for (int e = 1; e < 8; e++) if (sc[e] > sc[i1]) i1 = e;
      int i2 = -1;
      for (int e = 0; e < 8; e++) {
        if (e == i1) continue;
        if (i2 < 0 || sc[e] > sc[i2]) i2 = e;
      }
      float denom = sc[i1] + sc[i2] + 1e-6f;
      float* gr = g + (size_t)tok * E;
      #pragma unroll
      for (int e = 0; e < 8; e++) gr[e] = 0.f;
      gr[i1] = sc[i1] / denom;
      gr[i2] = sc[i2] / denom;
      sgbuf[tok] = 1.f / (1.f + expf(-raw[8]));
      for (int e = 0; e < 8; e++) atomicAdd(&s_scores[e], sc[e]);  // LDS
      int lt = wave * (GT / 4) + tt;
      int p1 = atomicAdd(&s_cnt[i1], 1);   // LDS
      int p2 = atomicAdd(&s_cnt[i2], 1);   // LDS
      s_e1[lt] = i1; s_p1[lt] = p1;
      s_e2[lt] = i2; s_p2[lt] = p2;
    }
  }
  __syncthreads();
  if (tid < 8) {
    s_base[tid] = atomicAdd(&counts[tid], s_cnt[tid]);   // 8 global atomics
    atomicAdd(&scoresums[tid], s_scores[tid]);           // 8 global atomics
  }
  __syncthreads();
  if (tid < GT) {
    int tok = blockIdx.x * GT + tid;
    int e1 = s_e1[tid], e2 = s_e2[tid];
    lists[e1 * N + s_base[e1] + s_p1[tid]] = (tok << 1);
    lists[e2 * N + s_base[e2] + s_p2[tid]] = (tok << 1) | 1;
  }
}

// ------------------------------------- pipelined MFMA GEMM mainloop (depth 2)
// Triple-buffered LDS; ONE raw s_barrier + one vmcnt(2) per iteration.
// Iter k: wait own tile-k loads (vmcnt(2): tile k+1 stays in flight) ->
// barrier (=> whole tile k valid across waves) -> ds_read+MFMA buf(k%3) ->
// prefetch tile k+2 into buf((k+2)%3) == buf((k-1)%3), last read at iter k-1,
// which all waves finished before passing barrier k. Last iter peeled (vmcnt 0).
__device__ __forceinline__ void mfma_loop64(
    const char* gA, const char* gB, char* As, char* Bs,
    int wave, int lane, int kIters, int mb, int nb, f32x4 acc[2][2]) {
  const int q = wave * 1024;                  // staging quarter base
  const int arow = lane & 15;
  const int koff = (lane >> 4) * 16;          // quad*8 elems * 2B
  // prologue: prefetch tiles 0,1
  __builtin_amdgcn_global_load_lds(GPTR(gA), LPTR(As + q), 16, 0, 0);
  __builtin_amdgcn_global_load_lds(GPTR(gB), LPTR(Bs + q), 16, 0, 0);
  __builtin_amdgcn_global_load_lds(GPTR(gA + 64), LPTR(As + BUF + q), 16, 0, 0);
  __builtin_amdgcn_global_load_lds(GPTR(gB + 64), LPTR(Bs + BUF + q), 16, 0, 0);
  int cur = 0, nxt = BUF, old = 2 * BUF;
  for (int kt = 0; kt < kIters - 1; ++kt) {
    WAIT_VM2();
    __builtin_amdgcn_s_barrier();
    bf16x8 a[2], b[2];
    #pragma unroll
    for (int i = 0; i < 2; ++i) {
      a[i] = *(const bf16x8*)(As + cur + (mb + i * 16 + arow) * 64 + koff);
      b[i] = *(const bf16x8*)(Bs + cur + (nb + i * 16 + arow) * 64 + koff);
    }
    #pragma unroll
    for (int i = 0; i < 2; ++i)
      #pragma unroll
      for (int j = 0; j < 2; ++j)
        acc[i][j] = __builtin_amdgcn_mfma_f32_16x16x32_bf16(a[i], b[j], acc[i][j], 0, 0, 0);
    if (kt + 2 < kIters) {
      const char* pA = gA + (size_t)(kt + 2) * (BK * 2);
      const char* pB = gB + (size_t)(kt + 2) * (BK * 2);
      __builtin_amdgcn_global_load_lds(GPTR(pA), LPTR(As + old + q), 16, 0, 0);
      __builtin_amdgcn_global_load_lds(GPTR(pB), LPTR(Bs + old + q), 16, 0, 0);
    }
    int t = cur; cur = nxt; nxt = old; old = t;
  }
  // peeled last iteration
  WAIT_VM0();
  __builtin_amdgcn_s_barrier();
  {
    bf16x8 a[2], b[2];
    #pragma unroll
    for (int i = 0; i < 2; ++i) {
      a[i] = *(const bf16x8*)(As + cur + (mb + i * 16 + arow) * 64 + koff);
      b[i] = *(const bf16x8*)(Bs + cur + (nb + i * 16 + arow) * 64 + koff);
    }
    #pragma unroll
    for (int i = 0; i < 2; ++i)
      #pragma unroll
      for (int j = 0; j < 2; ++j)
        acc[i][j] = __builtin_amdgcn_mfma_f32_16x16x32_bf16(a[i], b[j], acc[i][j], 0, 0, 0);
  }
}

#define GEMM_PROLOGUE64                                            \
  const int tid = threadIdx.x;                                     \
  const int lane = tid & 63, wave = tid >> 6;                      \
  const int srow = wave * 16 + (lane >> 2);  /* staging tile row */\
  const int scb = (lane & 3) * 16;           /* staging col byte */\
  const int mb = (wave & 1) * 32, nb = (wave >> 1) * 32;           \
  const int col = lane & 15, quad = lane >> 4;                     \
  __shared__ __align__(16) char As[3 * BUF];                       \
  __shared__ __align__(16) char Bs[3 * BUF];                       \
  f32x4 acc[2][2] = {};

// -------------------------------------------- expert up-proj (gathered GEMM)
__global__ __launch_bounds__(256) void up_kernel(
    const bf16* __restrict__ xtb, const bf16* __restrict__ w1b,
    const float* __restrict__ g, const int* __restrict__ lists,
    const int* __restrict__ counts, bf16* __restrict__ hb) {
  const int e = blockIdx.y;
  const int cnt = counts[e];
  const int m0 = blockIdx.x * BM;
  if (m0 >= cnt) return;
  const int h0 = blockIdx.z * BN;
  GEMM_PROLOGUE64
  __shared__ int toks[BM];
  if (tid < BM) toks[tid] = lists[e * N + min(m0 + tid, cnt - 1)];
  __syncthreads();
  const char* gA = (const char*)xtb + ((size_t)(toks[srow] >> 1) * C) * 2 + scb;
  const char* gB = (const char*)w1b + ((size_t)e * H * C + (size_t)(h0 + srow) * C) * 2 + scb;
  mfma_loop64(gA, gB, As, Bs, wave, lane, C / BK, mb, nb, acc);
  #pragma unroll
  for (int mi = 0; mi < 2; mi++) {
    #pragma unroll
    for (int r = 0; r < 4; r++) {
      int ml = mb + mi * 16 + quad * 4 + r;
      if (m0 + ml < cnt) {
        int packed = toks[ml];
        float gv = g[(size_t)(packed >> 1) * E + e];
        size_t base = (size_t)packed * H + h0 + nb;
        #pragma unroll
        for (int ni = 0; ni < 2; ni++) {
          float v = fmaxf(acc[mi][ni][r], 0.f);
          hb[base + ni * 16 + col] = (bf16)(v * v * gv);
        }
      }
    }
  }
}

// ------------------------------------------ expert down-proj (gathered GEMM)
__global__ __launch_bounds__(256) void down_kernel(
    const bf16* __restrict__ hb, const bf16* __restrict__ w2b,
    const int* __restrict__ lists, const int* __restrict__ counts,
    float* __restrict__ out) {
  const int e = blockIdx.y;
  const int cnt = counts[e];
  const int m0 = blockIdx.x * BM;
  if (m0 >= cnt) return;
  const int c0 = blockIdx.z * BN;
  GEMM_PROLOGUE64
  __shared__ int toks[BM];
  if (tid < BM) toks[tid] = lists[e * N + min(m0 + tid, cnt - 1)];
  __syncthreads();
  const char* gA = (const char*)hb + ((size_t)toks[srow] * H) * 2 + scb;
  const char* gB = (const char*)w2b + ((size_t)e * C * H + (size_t)(c0 + srow) * H) * 2 + scb;
  mfma_loop64(gA, gB, As, Bs, wave, lane, H / BK, mb, nb, acc);
  #pragma unroll
  for (int mi = 0; mi < 2; mi++) {
    #pragma unroll
    for (int r = 0; r < 4; r++) {
      int ml = mb + mi * 16 + quad * 4 + r;
      if (m0 + ml < cnt) {
        int tok = toks[ml] >> 1;
        float* orow = out + (size_t)tok * C + c0 + nb;
        #pragma unroll
        for (int ni = 0; ni < 2; ni++) atomicAdd(&orow[ni * 16 + col], acc[mi][ni][r]);
      }
    }
  }
}

// --------------------------------------------------- shared expert: k-proj
__global__ __launch_bounds__(256) void kproj_kernel(
    const bf16* __restrict__ xtb, const bf16* __restrict__ kwb,
    const float* __restrict__ rs2, const float* __restrict__ k_b,
    bf16* __restrict__ kkb) {
  const int n0 = blockIdx.x * BM;
  const int h0 = blockIdx.y * BN;
  GEMM_PROLOGUE64
  const char* gA = (const char*)xtb + ((size_t)(n0 + srow) * C) * 2 + scb;
  const char* gB = (const char*)kwb + ((size_t)(h0 + srow) * C) * 2 + scb;
  mfma_loop64(gA, gB, As, Bs, wave, lane, C / BK, mb, nb, acc);
  #pragma unroll
  for (int mi = 0; mi < 2; mi++) {
    #pragma unroll
    for (int r = 0; r < 4; r++) {
      int n = n0 + mb + mi * 16 + quad * 4 + r;
      float rs = rs2[n];
      #pragma unroll
      for (int ni = 0; ni < 2; ni++) {
        int h = h0 + nb + ni * 16 + col;
        float v = fmaf(acc[mi][ni][r], rs, k_b[h]);
        v = fmaxf(v, 0.f);
        kkb[(size_t)n * H + h] = (bf16)(v * v);
      }
    }
  }
}

// --------------------------------------------------- shared expert: v-proj
// split-K2: each slice atomicAdds its partial; slice 0 adds sg*v_b term.
__global__ __launch_bounds__(256) void vproj_kernel(
    const bf16* __restrict__ kkb, const bf16* __restrict__ vwb,
    const float* __restrict__ v_b, const float* __restrict__ sg,
    float* __restrict__ out) {
  const int n0 = blockIdx.x * BM;
  const int c0 = blockIdx.y * BN;
  const int ks = blockIdx.z;                 // 0 or 1: K-slice of H
  GEMM_PROLOGUE64
  const size_t kofs = (size_t)ks * (H / 2) * 2;   // byte offset into K
  const char* gA = (const char*)kkb + ((size_t)(n0 + srow) * H) * 2 + kofs + scb;
  const char* gB = (const char*)vwb + ((size_t)(c0 + srow) * H) * 2 + kofs + scb;
  mfma_loop64(gA, gB, As, Bs, wave, lane, (H / 2) / BK, mb, nb, acc);
  #pragma unroll
  for (int mi = 0; mi < 2; mi++) {
    #pragma unroll
    for (int r = 0; r < 4; r++) {
      int n = n0 + mb + mi * 16 + quad * 4 + r;
      float sgv = sg[n];
      #pragma unroll
      for (int ni = 0; ni < 2; ni++) {
        int c = c0 + nb + ni * 16 + col;
        float add = sgv * acc[mi][ni][r];
        if (ks == 0) add += sgv * v_b[c];
        atomicAdd(&out[(size_t)n * C + c], add);
      }
    }
  }
}

// -------------------------------------------------------------------- aux
__global__ void aux_kernel(const float* __restrict__ scoresums,
                           const int* __restrict__ counts,
                           float* __restrict__ out_aux) {
  if (threadIdx.x == 0) {
    float a = 0.f;
    for (int e = 0; e < 8; e++)
      a += (0.5f * (float)counts[e] * (1.f / N)) * (scoresums[e] * (1.f / N));
    out_aux[0] = 8.f * a * 0.01f;
  }
}

extern "C" void kernel_launch(void* const* d_in, const int* in_sizes, int n_in,
                              void* d_out, int out_size, void* d_ws, size_t ws_size,
                              hipStream_t stream) {
  (void)in_sizes; (void)n_in; (void)ws_size;
  const float* x   = (const float*)d_in[0];
  const float* gw  = (const float*)d_in[1];
  const float* w1  = (const float*)d_in[2];
  const float* w2  = (const float*)d_in[3];
  const float* sgw = (const float*)d_in[4];
  const float* k_w = (const float*)d_in[5];
  const float* k_b = (const float*)d_in[6];
  const float* v_w = (const float*)d_in[7];
  const float* v_b = (const float*)d_in[8];
  float* out = (float*)d_out;

  // workspace layout (~97 MiB)
  char* p = (char*)d_ws;
  auto alloc = [&](size_t bytes) { char* r = p; p += (bytes + 255) & ~255ull; return r; };
  bf16* xtb  = (bf16*)alloc((size_t)N * C * 2);
  bf16* w1b  = (bf16*)alloc((size_t)E * H * C * 2);
  bf16* w2b  = (bf16*)alloc((size_t)E * C * H * 2);
  bf16* kwb  = (bf16*)alloc((size_t)H * C * 2);
  bf16* vwb  = (bf16*)alloc((size_t)C * H * 2);
  bf16* hb   = (bf16*)alloc((size_t)2 * N * H * 2);  // [2N][H], packed-slot rows
  bf16* kkb  = hb;  // alias: down reads hb strictly before kproj writes kkb
  float* rs1 = (float*)alloc((size_t)N * 4);
  float* rs2 = (float*)alloc((size_t)N * 4);
  float* g   = (float*)alloc((size_t)N * E * 4);
  float* sg  = (float*)alloc((size_t)N * 4);
  float* scoresums = (float*)alloc(64);
  int* counts = (int*)alloc(64);
  int* lists  = (int*)alloc((size_t)E * N * 4);

  hipMemsetAsync(d_out, 0, (size_t)out_size * sizeof(float), stream);
  init_kernel<<<1, 32, 0, stream>>>(counts, scoresums);
  {
    const size_t total4 = ((size_t)E * H * C * 2 + (size_t)H * C * 2) / 4;  // float4 count
    cvt_all_kernel<<<(int)(total4 / 256), 256, 0, stream>>>(w1, w2, k_w, v_w, w1b, w2b, kwb, vwb);
  }
  rmsnorm_kernel<<<N, 256, 0, stream>>>(x, xtb, rs1, rs2);
  gate_kernel<<<N / GT, 256, 0, stream>>>(x, rs1, gw, sgw, g, sg, counts, lists, scoresums);
  up_kernel<<<dim3(N / BM, E, H / BN), 256, 0, stream>>>(xtb, w1b, g, lists, counts, hb);
  down_kernel<<<dim3(N / BM, E, C / BN), 256, 0, stream>>>(hb, w2b, lists, counts, out);
  kproj_kernel<<<dim3(N / BM, H / BN), 256, 0, stream>>>(xtb, kwb, rs2, k_b, kkb);
  vproj_kernel<<<dim3(N / BM, C / BN, 2), 256, 0, stream>>>(kkb, vwb, v_b, sg, out);
  aux_kernel<<<1, 64, 0, stream>>>(scoresums, counts, out + (size_t)N * C);
}

// Round 6
// 391.749 us; speedup vs baseline: 1.5082x; 1.5082x over previous
//
#include <hip/hip_runtime.h>
#include <hip/hip_bf16.h>
#include <stdint.h>

typedef __bf16 bf16;
typedef bf16 bf16x8 __attribute__((ext_vector_type(8)));
typedef bf16 bf16x4 __attribute__((ext_vector_type(4)));
typedef float f32x4 __attribute__((ext_vector_type(4)));

constexpr int N = 2048;   // tokens
constexpr int C = 1024;   // model dim
constexpr int H = 2048;   // hidden dim
constexpr int E = 8;      // experts
constexpr float EPS = 1.1920929e-07f;

constexpr int BM = 128, BN = 128, BK = 32;   // proven R3 m97 tile
constexpr int GT = 32;                       // tokens per gate block

// ---------------------------------------------------------------- small init
__global__ void init_kernel(int* counts, float* scoresums) {
  int t = threadIdx.x;
  if (t < E) counts[t] = 0;
  if (t < E) scoresums[t] = 0.f;
}

// ------------------------------------------------- fp32 -> bf16 cvt (merged)
__global__ void cvt_all_kernel(const float* __restrict__ w1, const float* __restrict__ w2,
                               const float* __restrict__ kw, const float* __restrict__ vw,
                               bf16* __restrict__ w1b, bf16* __restrict__ w2b,
                               bf16* __restrict__ kwb, bf16* __restrict__ vwb) {
  size_t i = (size_t)blockIdx.x * 256 + threadIdx.x;     // float4 units
  const size_t n1 = (size_t)E * H * C / 4;
  const size_t n2 = n1 * 2;
  const size_t n3 = n2 + (size_t)H * C / 4;
  const float4* src; bf16x4* dst; size_t off;
  if (i < n1)      { src = (const float4*)w1; dst = (bf16x4*)w1b; off = i; }
  else if (i < n2) { src = (const float4*)w2; dst = (bf16x4*)w2b; off = i - n1; }
  else if (i < n3) { src = (const float4*)kw; dst = (bf16x4*)kwb; off = i - n2; }
  else             { src = (const float4*)vw; dst = (bf16x4*)vwb; off = i - n3; }
  float4 v = src[off];
  bf16x4 o = { (bf16)v.x, (bf16)v.y, (bf16)v.z, (bf16)v.w };
  dst[off] = o;
}

// --------------------------------------------------------------- rmsnorm(x)
__global__ void rmsnorm_kernel(const float* __restrict__ x,
                               bf16* __restrict__ xtb,
                               float* __restrict__ rs1_arr,
                               float* __restrict__ rs2_arr) {
  int n = blockIdx.x;
  int tid = threadIdx.x;                      // 256 threads, 1 float4 each
  float4 v = ((const float4*)(x + (size_t)n * C))[tid];
  float ss = v.x*v.x + v.y*v.y + v.z*v.z + v.w*v.w;
  #pragma unroll
  for (int off = 32; off > 0; off >>= 1) ss += __shfl_down(ss, off, 64);
  __shared__ float red[4];
  __shared__ float tot;
  int wave = tid >> 6, lane = tid & 63;
  if (lane == 0) red[wave] = ss;
  __syncthreads();
  if (tid == 0) tot = red[0] + red[1] + red[2] + red[3];
  __syncthreads();
  float sumsq = tot;
  float rs1 = rsqrtf(sumsq * (1.f / C) + EPS);
  bf16x4 o = { (bf16)(v.x*rs1), (bf16)(v.y*rs1), (bf16)(v.z*rs1), (bf16)(v.w*rs1) };
  ((bf16x4*)(xtb + (size_t)n * C))[tid] = o;
  if (tid == 0) {
    rs1_arr[n] = rs1;
    float m2 = sumsq * rs1 * rs1 * (1.f / C);  // mean(xt^2) exactly
    rs2_arr[n] = rsqrtf(m2 + EPS);
  }
}

// ------------------------------------------------------------------- gating
__global__ __launch_bounds__(256) void gate_kernel(
    const float* __restrict__ x, const float* __restrict__ rs1_arr,
    const float* __restrict__ gate_w, const float* __restrict__ sgw,
    float* __restrict__ g, float* __restrict__ sgbuf,
    int* __restrict__ counts, int* __restrict__ lists,
    float* __restrict__ scoresums) {
  __shared__ float wsm[9][1024];   // 36 KB: 8 expert rows + shared-gate row
  __shared__ float s_scores[8];
  __shared__ int   s_cnt[8];
  __shared__ int   s_base[8];
  __shared__ int   s_e1[GT], s_p1[GT], s_e2[GT], s_p2[GT];
  const int tid = threadIdx.x, lane = tid & 63, wave = tid >> 6;
  for (int i = tid; i < 9 * 1024; i += 256) {
    int e = i >> 10, c = i & 1023;
    wsm[e][c] = (e < 8) ? gate_w[i] : sgw[c];
  }
  if (tid < 8) { s_scores[tid] = 0.f; s_cnt[tid] = 0; }
  __syncthreads();

  const int tok0 = blockIdx.x * GT + wave * (GT / 4);
  for (int tt = 0; tt < GT / 4; ++tt) {
    const int tok = tok0 + tt;
    const float* xr = x + (size_t)tok * C;
    float acc[9];
    #pragma unroll
    for (int e = 0; e < 9; e++) acc[e] = 0.f;
    #pragma unroll
    for (int k = 0; k < 16; ++k) {
      int c = k * 64 + lane;
      float xv = xr[c];
      #pragma unroll
      for (int e = 0; e < 9; e++) acc[e] = fmaf(xv, wsm[e][c], acc[e]);
    }
    #pragma unroll
    for (int e = 0; e < 9; e++) {
      float v = acc[e];
      #pragma unroll
      for (int off = 32; off > 0; off >>= 1) v += __shfl_xor(v, off, 64);
      acc[e] = v;
    }
    if (lane == 0) {
      float rs1 = rs1_arr[tok];
      float raw[9];
      #pragma unroll
      for (int e = 0; e < 9; e++) raw[e] = acc[e] * rs1;
      float m = raw[0];
      for (int e = 1; e < 8; e++) m = fmaxf(m, raw[e]);
      float sc[8], s = 0.f;
      for (int e = 0; e < 8; e++) { sc[e] = expf(raw[e] - m); s += sc[e]; }
      float inv = 1.f / s;
      for (int e = 0; e < 8; e++) sc[e] *= inv;
      int i1 = 0;
      for (int e = 1; e < 8; e++) if (sc[e] > sc[i1]) i1 = e;
      int i2 = -1;
      for (int e = 0; e < 8; e++) {
        if (e == i1) continue;
        if (i2 < 0 || sc[e] > sc[i2]) i2 = e;
      }
      float denom = sc[i1] + sc[i2] + 1e-6f;
      float* gr = g + (size_t)tok * E;
      #pragma unroll
      for (int e = 0; e < 8; e++) gr[e] = 0.f;
      gr[i1] = sc[i1] / denom;
      gr[i2] = sc[i2] / denom;
      sgbuf[tok] = 1.f / (1.f + expf(-raw[8]));
      for (int e = 0; e < 8; e++) atomicAdd(&s_scores[e], sc[e]);  // LDS
      int lt = wave * (GT / 4) + tt;
      int p1 = atomicAdd(&s_cnt[i1], 1);   // LDS
      int p2 = atomicAdd(&s_cnt[i2], 1);   // LDS
      s_e1[lt] = i1; s_p1[lt] = p1;
      s_e2[lt] = i2; s_p2[lt] = p2;
    }
  }
  __syncthreads();
  if (tid < 8) {
    s_base[tid] = atomicAdd(&counts[tid], s_cnt[tid]);   // 8 global atomics
    atomicAdd(&scoresums[tid], s_scores[tid]);           // 8 global atomics
  }
  __syncthreads();
  if (tid < GT) {
    int tok = blockIdx.x * GT + tid;
    int e1 = s_e1[tid], e2 = s_e2[tid];
    lists[e1 * N + s_base[e1] + s_p1[tid]] = (tok << 1);
    lists[e2 * N + s_base[e2] + s_p2[tid]] = (tok << 1) | 1;
  }
}

// -------------------------------------------------------- MFMA GEMM mainloop
// Proven R3 structure: 128x128, BK=32, 4 waves 2x2, global_load_lds width=16,
// plain __syncthreads (compiler-managed waitcnt).
__device__ __forceinline__ void mfma_loop(
    const char* gA0, const char* gA1, const char* gB0, const char* gB1,
    char* As, char* Bs, int wave, int lane, int kIters,
    int mb, int nb, f32x4 acc[4][4]) {
  const int l0 = wave * 2048, l1 = l0 + 1024;   // wave-uniform LDS bases
  const int arow = lane & 15;
  const int koff = (lane >> 4) * 16;            // quad*8 elems * 2B
  for (int kt = 0; kt < kIters; ++kt) {
    __builtin_amdgcn_global_load_lds((__attribute__((address_space(1))) void*)gA0,
                                     (__attribute__((address_space(3))) void*)(As + l0), 16, 0, 0);
    __builtin_amdgcn_global_load_lds((__attribute__((address_space(1))) void*)gA1,
                                     (__attribute__((address_space(3))) void*)(As + l1), 16, 0, 0);
    __builtin_amdgcn_global_load_lds((__attribute__((address_space(1))) void*)gB0,
                                     (__attribute__((address_space(3))) void*)(Bs + l0), 16, 0, 0);
    __builtin_amdgcn_global_load_lds((__attribute__((address_space(1))) void*)gB1,
                                     (__attribute__((address_space(3))) void*)(Bs + l1), 16, 0, 0);
    gA0 += BK * 2; gA1 += BK * 2; gB0 += BK * 2; gB1 += BK * 2;
    __syncthreads();
    bf16x8 a[4], b[4];
    #pragma unroll
    for (int i = 0; i < 4; ++i) {
      a[i] = *(const bf16x8*)(As + (mb + i * 16 + arow) * 64 + koff);
      b[i] = *(const bf16x8*)(Bs + (nb + i * 16 + arow) * 64 + koff);
    }
    #pragma unroll
    for (int i = 0; i < 4; ++i)
      #pragma unroll
      for (int j = 0; j < 4; ++j)
        acc[i][j] = __builtin_amdgcn_mfma_f32_16x16x32_bf16(a[i], b[j], acc[i][j], 0, 0, 0);
    __syncthreads();
  }
}

#define GEMM_PROLOGUE                                              \
  const int tid = threadIdx.x;                                     \
  const int lane = tid & 63, wave = tid >> 6;                      \
  const int sr0 = wave * 32 + (lane >> 2), sr1 = sr0 + 16;         \
  const int scb = (lane & 3) * 16; /* staging col bytes */         \
  const int mb = (wave & 1) * 64, nb = (wave >> 1) * 64;           \
  const int col = lane & 15, quad = lane >> 4;                     \
  __shared__ __align__(16) char As[BM * BK * 2];                   \
  __shared__ __align__(16) char Bs[BN * BK * 2];                   \
  f32x4 acc[4][4] = {};

// -------------------------------------------- expert up-proj (gathered GEMM)
// grid (H/BN, N/BM, E): x fully populated -> active blocks span all XCDs
__global__ void up_kernel(const bf16* __restrict__ xtb, const bf16* __restrict__ w1b,
                          const float* __restrict__ g, const int* __restrict__ lists,
                          const int* __restrict__ counts, bf16* __restrict__ hb) {
  const int e = blockIdx.z;
  const int cnt = counts[e];
  const int m0 = blockIdx.y * BM;
  if (m0 >= cnt) return;
  const int h0 = blockIdx.x * BN;
  GEMM_PROLOGUE
  __shared__ int toks[BM];
  if (tid < BM) toks[tid] = lists[e * N + min(m0 + tid, cnt - 1)];
  __syncthreads();
  const char* gA0 = (const char*)xtb + ((size_t)(toks[sr0] >> 1) * C) * 2 + scb;
  const char* gA1 = (const char*)xtb + ((size_t)(toks[sr1] >> 1) * C) * 2 + scb;
  const char* gB0 = (const char*)w1b + ((size_t)e * H * C + (size_t)(h0 + sr0) * C) * 2 + scb;
  const char* gB1 = (const char*)w1b + ((size_t)e * H * C + (size_t)(h0 + sr1) * C) * 2 + scb;
  mfma_loop(gA0, gA1, gB0, gB1, As, Bs, wave, lane, C / BK, mb, nb, acc);
  #pragma unroll
  for (int mi = 0; mi < 4; mi++) {
    #pragma unroll
    for (int r = 0; r < 4; r++) {
      int ml = mb + mi * 16 + quad * 4 + r;
      if (m0 + ml < cnt) {
        int packed = toks[ml];
        float gv = g[(size_t)(packed >> 1) * E + e];
        size_t base = (size_t)packed * H + h0 + nb;
        #pragma unroll
        for (int ni = 0; ni < 4; ni++) {
          float v = fmaxf(acc[mi][ni][r], 0.f);
          hb[base + ni * 16 + col] = (bf16)(v * v * gv);
        }
      }
    }
  }
}

// ------------------------------------------ expert down-proj (gathered GEMM)
// grid (C/BN, N/BM, E*2): split-K2 over H; z = e*2+ks. Atomic scatter output.
__global__ void down_kernel(const bf16* __restrict__ hb, const bf16* __restrict__ w2b,
                            const int* __restrict__ lists, const int* __restrict__ counts,
                            float* __restrict__ out) {
  const int e = blockIdx.z >> 1, ks = blockIdx.z & 1;
  const int cnt = counts[e];
  const int m0 = blockIdx.y * BM;
  if (m0 >= cnt) return;
  const int c0 = blockIdx.x * BN;
  GEMM_PROLOGUE
  __shared__ int toks[BM];
  if (tid < BM) toks[tid] = lists[e * N + min(m0 + tid, cnt - 1)];
  __syncthreads();
  const size_t kofs = (size_t)ks * (H / 2) * 2;   // byte offset into K
  const char* gA0 = (const char*)hb + ((size_t)toks[sr0] * H) * 2 + kofs + scb;
  const char* gA1 = (const char*)hb + ((size_t)toks[sr1] * H) * 2 + kofs + scb;
  const char* gB0 = (const char*)w2b + ((size_t)e * C * H + (size_t)(c0 + sr0) * H) * 2 + kofs + scb;
  const char* gB1 = (const char*)w2b + ((size_t)e * C * H + (size_t)(c0 + sr1) * H) * 2 + kofs + scb;
  mfma_loop(gA0, gA1, gB0, gB1, As, Bs, wave, lane, (H / 2) / BK, mb, nb, acc);
  #pragma unroll
  for (int mi = 0; mi < 4; mi++) {
    #pragma unroll
    for (int r = 0; r < 4; r++) {
      int ml = mb + mi * 16 + quad * 4 + r;
      if (m0 + ml < cnt) {
        int tok = toks[ml] >> 1;
        float* orow = out + (size_t)tok * C + c0 + nb;
        #pragma unroll
        for (int ni = 0; ni < 4; ni++) atomicAdd(&orow[ni * 16 + col], acc[mi][ni][r]);
      }
    }
  }
}

// --------------------------------------------------- shared expert: k-proj
// kk = bf16( relu(rs2*(xt.k_w^T) + k_b)^2 );  grid (N/BM=16, H/BN=16)
__global__ void kproj_kernel(const bf16* __restrict__ xtb, const bf16* __restrict__ kwb,
                             const float* __restrict__ rs2, const float* __restrict__ k_b,
                             bf16* __restrict__ kkb) {
  const int n0 = blockIdx.x * BM;
  const int h0 = blockIdx.y * BN;
  GEMM_PROLOGUE
  const char* gA0 = (const char*)xtb + ((size_t)(n0 + sr0) * C) * 2 + scb;
  const char* gA1 = (const char*)xtb + ((size_t)(n0 + sr1) * C) * 2 + scb;
  const char* gB0 = (const char*)kwb + ((size_t)(h0 + sr0) * C) * 2 + scb;
  const char* gB1 = (const char*)kwb + ((size_t)(h0 + sr1) * C) * 2 + scb;
  mfma_loop(gA0, gA1, gB0, gB1, As, Bs, wave, lane, C / BK, mb, nb, acc);
  #pragma unroll
  for (int mi = 0; mi < 4; mi++) {
    #pragma unroll
    for (int r = 0; r < 4; r++) {
      int n = n0 + mb + mi * 16 + quad * 4 + r;
      float rs = rs2[n];
      #pragma unroll
      for (int ni = 0; ni < 4; ni++) {
        int h = h0 + nb + ni * 16 + col;
        float v = fmaf(acc[mi][ni][r], rs, k_b[h]);
        v = fmaxf(v, 0.f);
        kkb[(size_t)n * H + h] = (bf16)(v * v);
      }
    }
  }
}

// --------------------------------------------------- shared expert: v-proj
// out += sg*(kk.v_w^T + v_b); split-K2 over H, atomicAdd epilogue (commutes
// with down's atomics); slice 0 carries the sg*v_b term.
__global__ void vproj_kernel(const bf16* __restrict__ kkb, const bf16* __restrict__ vwb,
                             const float* __restrict__ v_b, const float* __restrict__ sg,
                             float* __restrict__ out) {
  const int n0 = blockIdx.x * BM;
  const int c0 = blockIdx.y * BN;
  const int ks = blockIdx.z;
  GEMM_PROLOGUE
  const size_t kofs = (size_t)ks * (H / 2) * 2;
  const char* gA0 = (const char*)kkb + ((size_t)(n0 + sr0) * H) * 2 + kofs + scb;
  const char* gA1 = (const char*)kkb + ((size_t)(n0 + sr1) * H) * 2 + kofs + scb;
  const char* gB0 = (const char*)vwb + ((size_t)(c0 + sr0) * H) * 2 + kofs + scb;
  const char* gB1 = (const char*)vwb + ((size_t)(c0 + sr1) * H) * 2 + kofs + scb;
  mfma_loop(gA0, gA1, gB0, gB1, As, Bs, wave, lane, (H / 2) / BK, mb, nb, acc);
  #pragma unroll
  for (int mi = 0; mi < 4; mi++) {
    #pragma unroll
    for (int r = 0; r < 4; r++) {
      int n = n0 + mb + mi * 16 + quad * 4 + r;
      float sgv = sg[n];
      #pragma unroll
      for (int ni = 0; ni < 4; ni++) {
        int c = c0 + nb + ni * 16 + col;
        float add = sgv * acc[mi][ni][r];
        if (ks == 0) add += sgv * v_b[c];
        atomicAdd(&out[(size_t)n * C + c], add);
      }
    }
  }
}

// -------------------------------------------------------------------- aux
__global__ void aux_kernel(const float* __restrict__ scoresums,
                           const int* __restrict__ counts,
                           float* __restrict__ out_aux) {
  if (threadIdx.x == 0) {
    float a = 0.f;
    for (int e = 0; e < 8; e++)
      a += (0.5f * (float)counts[e] * (1.f / N)) * (scoresums[e] * (1.f / N));
    out_aux[0] = 8.f * a * 0.01f;
  }
}

extern "C" void kernel_launch(void* const* d_in, const int* in_sizes, int n_in,
                              void* d_out, int out_size, void* d_ws, size_t ws_size,
                              hipStream_t stream) {
  (void)in_sizes; (void)n_in; (void)ws_size;
  const float* x   = (const float*)d_in[0];
  const float* gw  = (const float*)d_in[1];
  const float* w1  = (const float*)d_in[2];
  const float* w2  = (const float*)d_in[3];
  const float* sgw = (const float*)d_in[4];
  const float* k_w = (const float*)d_in[5];
  const float* k_b = (const float*)d_in[6];
  const float* v_w = (const float*)d_in[7];
  const float* v_b = (const float*)d_in[8];
  float* out = (float*)d_out;

  // workspace layout (~97 MiB)
  char* p = (char*)d_ws;
  auto alloc = [&](size_t bytes) { char* r = p; p += (bytes + 255) & ~255ull; return r; };
  bf16* xtb  = (bf16*)alloc((size_t)N * C * 2);
  bf16* w1b  = (bf16*)alloc((size_t)E * H * C * 2);
  bf16* w2b  = (bf16*)alloc((size_t)E * C * H * 2);
  bf16* kwb  = (bf16*)alloc((size_t)H * C * 2);
  bf16* vwb  = (bf16*)alloc((size_t)C * H * 2);
  bf16* hb   = (bf16*)alloc((size_t)2 * N * H * 2);  // [2N][H], packed-slot rows
  bf16* kkb  = hb;  // alias: down reads hb strictly before kproj writes kkb
  float* rs1 = (float*)alloc((size_t)N * 4);
  float* rs2 = (float*)alloc((size_t)N * 4);
  float* g   = (float*)alloc((size_t)N * E * 4);
  float* sg  = (float*)alloc((size_t)N * 4);
  float* scoresums = (float*)alloc(64);
  int* counts = (int*)alloc(64);
  int* lists  = (int*)alloc((size_t)E * N * 4);

  hipMemsetAsync(d_out, 0, (size_t)out_size * sizeof(float), stream);
  init_kernel<<<1, 32, 0, stream>>>(counts, scoresums);
  {
    const size_t total4 = ((size_t)E * H * C * 2 + (size_t)H * C * 2) / 4;  // float4 count
    cvt_all_kernel<<<(int)(total4 / 256), 256, 0, stream>>>(w1, w2, k_w, v_w, w1b, w2b, kwb, vwb);
  }
  rmsnorm_kernel<<<N, 256, 0, stream>>>(x, xtb, rs1, rs2);
  gate_kernel<<<N / GT, 256, 0, stream>>>(x, rs1, gw, sgw, g, sg, counts, lists, scoresums);
  up_kernel<<<dim3(H / BN, N / BM, E), 256, 0, stream>>>(xtb, w1b, g, lists, counts, hb);
  down_kernel<<<dim3(C / BN, N / BM, E * 2), 256, 0, stream>>>(hb, w2b, lists, counts, out);
  kproj_kernel<<<dim3(N / BM, H / BN), 256, 0, stream>>>(xtb, kwb, rs2, k_b, kkb);
  vproj_kernel<<<dim3(N / BM, C / BN, 2), 256, 0, stream>>>(kkb, vwb, v_b, sg, out);
  aux_kernel<<<1, 64, 0, stream>>>(scoresums, counts, out + (size_t)N * C);
}

// Round 7
// 322.832 us; speedup vs baseline: 1.8301x; 1.2135x over previous
//
#include <hip/hip_runtime.h>
#include <hip/hip_bf16.h>
#include <stdint.h>

typedef __bf16 bf16;
typedef bf16 bf16x8 __attribute__((ext_vector_type(8)));
typedef bf16 bf16x4 __attribute__((ext_vector_type(4)));
typedef float f32x4 __attribute__((ext_vector_type(4)));

constexpr int N = 2048;   // tokens
constexpr int C = 1024;   // model dim
constexpr int H = 2048;   // hidden dim
constexpr int E = 8;      // experts
constexpr float EPS = 1.1920929e-07f;

constexpr int BM = 128, BN = 128, BK = 32;   // proven R3/R6 m97 tile
constexpr int GT = 32;                       // tokens per gate block

// grid decode constants
constexpr int PREP_GATE = N / GT;                       // 64
constexpr int PREP_RMS  = N;                            // 2048
constexpr int CVT1_F4   = (E * H * C + H * C) / 4;      // w1 + k_w float4s
constexpr int CVT1_BLK  = CVT1_F4 / 1024;               // 4608
constexpr int PREP_TOTAL = PREP_GATE + PREP_RMS + CVT1_BLK;

constexpr int P1_UP    = (H / BN) * (N / BM) * E;       // 2048
constexpr int P1_KP    = (N / BM) * (H / BN);           // 256
constexpr int CVT2_F4  = (E * C * H + C * H) / 4;       // w2 + v_w float4s
constexpr int CVT2_BLK = CVT2_F4 / 1024;                // 4608
constexpr int P1_TOTAL = P1_UP + P1_KP + CVT2_BLK;

constexpr int P2_DOWN  = (C / BN) * (N / BM) * (E * 2); // 2048 (split-K2)
constexpr int P2_VP    = (N / BM) * (C / BN) * 2;       // 256  (split-K2)
constexpr int P2_TOTAL = P2_DOWN + P2_VP;

// ----------------------------------------------------- fp32->bf16 cvt helper
// one block converts 1024 float4s (4/thread, stride-256) across two arrays
__device__ __forceinline__ void cvt_pair(const float* __restrict__ s1, bf16* __restrict__ d1,
                                         size_t n1, const float* __restrict__ s2,
                                         bf16* __restrict__ d2, int cbx) {
  size_t base = (size_t)cbx * 1024 + threadIdx.x;
  #pragma unroll
  for (int j = 0; j < 4; ++j) {
    size_t i = base + (size_t)j * 256;
    if (i < n1) {
      float4 v = ((const float4*)s1)[i];
      bf16x4 o = { (bf16)v.x, (bf16)v.y, (bf16)v.z, (bf16)v.w };
      ((bf16x4*)d1)[i] = o;
    } else {
      size_t k = i - n1;
      float4 v = ((const float4*)s2)[k];
      bf16x4 o = { (bf16)v.x, (bf16)v.y, (bf16)v.z, (bf16)v.w };
      ((bf16x4*)d2)[k] = o;
    }
  }
}

// ====================================================================== PREP
// bx [0,64): gate (self-computed rs1)  [64,2112): rmsnorm  [2112,...): cvt w1+kw
__global__ __launch_bounds__(256) void prep_kernel(
    const float* __restrict__ x, const float* __restrict__ gate_w,
    const float* __restrict__ sgw, const float* __restrict__ w1,
    const float* __restrict__ kw,
    bf16* __restrict__ xtb, float* __restrict__ rs2_arr,
    float* __restrict__ g, float* __restrict__ sgbuf,
    int* __restrict__ counts, int* __restrict__ lists,
    float* __restrict__ scoresums,
    bf16* __restrict__ w1b, bf16* __restrict__ kwb) {
  __shared__ float wsm[9][1024];   // 36 KB (gate branch only)
  __shared__ float s_scores[8];
  __shared__ int   s_cnt[8];
  __shared__ int   s_base[8];
  __shared__ int   s_e1[GT], s_p1[GT], s_e2[GT], s_p2[GT];
  const int bx = blockIdx.x;
  const int tid = threadIdx.x, lane = tid & 63, wave = tid >> 6;

  if (bx >= PREP_GATE + PREP_RMS) {            // ---- cvt w1 + k_w
    cvt_pair(w1, w1b, (size_t)E * H * C / 4, kw, kwb, bx - PREP_GATE - PREP_RMS);
    return;
  }
  if (bx >= PREP_GATE) {                       // ---- rmsnorm token row
    int n = bx - PREP_GATE;
    float4 v = ((const float4*)(x + (size_t)n * C))[tid];
    float ss = v.x*v.x + v.y*v.y + v.z*v.z + v.w*v.w;
    #pragma unroll
    for (int off = 32; off > 0; off >>= 1) ss += __shfl_down(ss, off, 64);
    __shared__ float red[4];
    __shared__ float tot;
    if (lane == 0) red[wave] = ss;
    __syncthreads();
    if (tid == 0) tot = red[0] + red[1] + red[2] + red[3];
    __syncthreads();
    float sumsq = tot;
    float rs1 = rsqrtf(sumsq * (1.f / C) + EPS);
    bf16x4 o = { (bf16)(v.x*rs1), (bf16)(v.y*rs1), (bf16)(v.z*rs1), (bf16)(v.w*rs1) };
    ((bf16x4*)(xtb + (size_t)n * C))[tid] = o;
    if (tid == 0) {
      float m2 = sumsq * rs1 * rs1 * (1.f / C);  // mean(xt^2) exactly
      rs2_arr[n] = rsqrtf(m2 + EPS);
    }
    return;
  }
  // --------------------------------------------------------------- gate
  for (int i = tid; i < 9 * 1024; i += 256) {
    int e = i >> 10, c = i & 1023;
    wsm[e][c] = (e < 8) ? gate_w[i] : sgw[c];
  }
  if (tid < 8) { s_scores[tid] = 0.f; s_cnt[tid] = 0; }
  __syncthreads();

  const int tok0 = bx * GT + wave * (GT / 4);
  for (int tt = 0; tt < GT / 4; ++tt) {
    const int tok = tok0 + tt;
    const float* xr = x + (size_t)tok * C;
    float acc[10];
    #pragma unroll
    for (int e = 0; e < 10; e++) acc[e] = 0.f;
    #pragma unroll
    for (int k = 0; k < 16; ++k) {
      int c = k * 64 + lane;
      float xv = xr[c];
      #pragma unroll
      for (int e = 0; e < 9; e++) acc[e] = fmaf(xv, wsm[e][c], acc[e]);
      acc[9] = fmaf(xv, xv, acc[9]);           // sum(x^2) for self rs1
    }
    #pragma unroll
    for (int e = 0; e < 10; e++) {
      float v = acc[e];
      #pragma unroll
      for (int off = 32; off > 0; off >>= 1) v += __shfl_xor(v, off, 64);
      acc[e] = v;
    }
    if (lane == 0) {
      float rs1 = rsqrtf(acc[9] * (1.f / C) + EPS);
      float raw[9];
      #pragma unroll
      for (int e = 0; e < 9; e++) raw[e] = acc[e] * rs1;
      float m = raw[0];
      for (int e = 1; e < 8; e++) m = fmaxf(m, raw[e]);
      float sc[8], s = 0.f;
      for (int e = 0; e < 8; e++) { sc[e] = expf(raw[e] - m); s += sc[e]; }
      float inv = 1.f / s;
      for (int e = 0; e < 8; e++) sc[e] *= inv;
      int i1 = 0;
      for (int e = 1; e < 8; e++) if (sc[e] > sc[i1]) i1 = e;
      int i2 = -1;
      for (int e = 0; e < 8; e++) {
        if (e == i1) continue;
        if (i2 < 0 || sc[e] > sc[i2]) i2 = e;
      }
      float denom = sc[i1] + sc[i2] + 1e-6f;
      float* gr = g + (size_t)tok * E;
      #pragma unroll
      for (int e = 0; e < 8; e++) gr[e] = 0.f;
      gr[i1] = sc[i1] / denom;
      gr[i2] = sc[i2] / denom;
      sgbuf[tok] = 1.f / (1.f + expf(-raw[8]));
      for (int e = 0; e < 8; e++) atomicAdd(&s_scores[e], sc[e]);  // LDS
      int lt = wave * (GT / 4) + tt;
      int p1 = atomicAdd(&s_cnt[i1], 1);   // LDS
      int p2 = atomicAdd(&s_cnt[i2], 1);   // LDS
      s_e1[lt] = i1; s_p1[lt] = p1;
      s_e2[lt] = i2; s_p2[lt] = p2;
    }
  }
  __syncthreads();
  if (tid < 8) {
    s_base[tid] = atomicAdd(&counts[tid], s_cnt[tid]);   // 8 global atomics
    atomicAdd(&scoresums[tid], s_scores[tid]);           // 8 global atomics
  }
  __syncthreads();
  if (tid < GT) {
    int tok = bx * GT + tid;
    int e1 = s_e1[tid], e2 = s_e2[tid];
    lists[e1 * N + s_base[e1] + s_p1[tid]] = (tok << 1);
    lists[e2 * N + s_base[e2] + s_p2[tid]] = (tok << 1) | 1;
  }
}

// -------------------------------------------------------- MFMA GEMM mainloop
// Proven R3/R6 structure: 128x128, BK=32, 4 waves 2x2, global_load_lds w=16.
__device__ __forceinline__ void mfma_loop(
    const char* gA0, const char* gA1, const char* gB0, const char* gB1,
    char* As, char* Bs, int wave, int lane, int kIters,
    int mb, int nb, f32x4 acc[4][4]) {
  const int l0 = wave * 2048, l1 = l0 + 1024;   // wave-uniform LDS bases
  const int arow = lane & 15;
  const int koff = (lane >> 4) * 16;            // quad*8 elems * 2B
  for (int kt = 0; kt < kIters; ++kt) {
    __builtin_amdgcn_global_load_lds((__attribute__((address_space(1))) void*)gA0,
                                     (__attribute__((address_space(3))) void*)(As + l0), 16, 0, 0);
    __builtin_amdgcn_global_load_lds((__attribute__((address_space(1))) void*)gA1,
                                     (__attribute__((address_space(3))) void*)(As + l1), 16, 0, 0);
    __builtin_amdgcn_global_load_lds((__attribute__((address_space(1))) void*)gB0,
                                     (__attribute__((address_space(3))) void*)(Bs + l0), 16, 0, 0);
    __builtin_amdgcn_global_load_lds((__attribute__((address_space(1))) void*)gB1,
                                     (__attribute__((address_space(3))) void*)(Bs + l1), 16, 0, 0);
    gA0 += BK * 2; gA1 += BK * 2; gB0 += BK * 2; gB1 += BK * 2;
    __syncthreads();
    bf16x8 a[4], b[4];
    #pragma unroll
    for (int i = 0; i < 4; ++i) {
      a[i] = *(const bf16x8*)(As + (mb + i * 16 + arow) * 64 + koff);
      b[i] = *(const bf16x8*)(Bs + (nb + i * 16 + arow) * 64 + koff);
    }
    #pragma unroll
    for (int i = 0; i < 4; ++i)
      #pragma unroll
      for (int j = 0; j < 4; ++j)
        acc[i][j] = __builtin_amdgcn_mfma_f32_16x16x32_bf16(a[i], b[j], acc[i][j], 0, 0, 0);
    __syncthreads();
  }
}

#define GEMM_VARS                                                  \
  const int tid = threadIdx.x;                                     \
  const int lane = tid & 63, wave = tid >> 6;                      \
  const int sr0 = wave * 32 + (lane >> 2), sr1 = sr0 + 16;         \
  const int scb = (lane & 3) * 16; /* staging col bytes */         \
  const int mb = (wave & 1) * 64, nb = (wave >> 1) * 64;           \
  const int col = lane & 15, quad = lane >> 4;                     \
  f32x4 acc[4][4] = {};

// ---------------------------------------------------------------- GEMM bodies
__device__ __forceinline__ void run_up(
    const bf16* __restrict__ xtb, const bf16* __restrict__ w1b,
    const float* __restrict__ g, const int* __restrict__ lists,
    const int* __restrict__ counts, bf16* __restrict__ hb,
    int e, int m0, int h0, char* As, char* Bs, int* toks) {
  const int cnt = counts[e];
  if (m0 >= cnt) return;
  GEMM_VARS
  if (tid < BM) toks[tid] = lists[e * N + min(m0 + tid, cnt - 1)];
  __syncthreads();
  const char* gA0 = (const char*)xtb + ((size_t)(toks[sr0] >> 1) * C) * 2 + scb;
  const char* gA1 = (const char*)xtb + ((size_t)(toks[sr1] >> 1) * C) * 2 + scb;
  const char* gB0 = (const char*)w1b + ((size_t)e * H * C + (size_t)(h0 + sr0) * C) * 2 + scb;
  const char* gB1 = (const char*)w1b + ((size_t)e * H * C + (size_t)(h0 + sr1) * C) * 2 + scb;
  mfma_loop(gA0, gA1, gB0, gB1, As, Bs, wave, lane, C / BK, mb, nb, acc);
  #pragma unroll
  for (int mi = 0; mi < 4; mi++) {
    #pragma unroll
    for (int r = 0; r < 4; r++) {
      int ml = mb + mi * 16 + quad * 4 + r;
      if (m0 + ml < cnt) {
        int packed = toks[ml];
        float gv = g[(size_t)(packed >> 1) * E + e];
        size_t base = (size_t)packed * H + h0 + nb;
        #pragma unroll
        for (int ni = 0; ni < 4; ni++) {
          float v = fmaxf(acc[mi][ni][r], 0.f);
          hb[base + ni * 16 + col] = (bf16)(v * v * gv);
        }
      }
    }
  }
}

__device__ __forceinline__ void run_kproj(
    const bf16* __restrict__ xtb, const bf16* __restrict__ kwb,
    const float* __restrict__ rs2, const float* __restrict__ k_b,
    bf16* __restrict__ kkb, int n0, int h0, char* As, char* Bs) {
  GEMM_VARS
  const char* gA0 = (const char*)xtb + ((size_t)(n0 + sr0) * C) * 2 + scb;
  const char* gA1 = (const char*)xtb + ((size_t)(n0 + sr1) * C) * 2 + scb;
  const char* gB0 = (const char*)kwb + ((size_t)(h0 + sr0) * C) * 2 + scb;
  const char* gB1 = (const char*)kwb + ((size_t)(h0 + sr1) * C) * 2 + scb;
  mfma_loop(gA0, gA1, gB0, gB1, As, Bs, wave, lane, C / BK, mb, nb, acc);
  #pragma unroll
  for (int mi = 0; mi < 4; mi++) {
    #pragma unroll
    for (int r = 0; r < 4; r++) {
      int n = n0 + mb + mi * 16 + quad * 4 + r;
      float rs = rs2[n];
      #pragma unroll
      for (int ni = 0; ni < 4; ni++) {
        int h = h0 + nb + ni * 16 + col;
        float v = fmaf(acc[mi][ni][r], rs, k_b[h]);
        v = fmaxf(v, 0.f);
        kkb[(size_t)n * H + h] = (bf16)(v * v);
      }
    }
  }
}

__device__ __forceinline__ void run_down(
    const bf16* __restrict__ hb, const bf16* __restrict__ w2b,
    const int* __restrict__ lists, const int* __restrict__ counts,
    float* __restrict__ out, int e, int ks, int m0, int c0,
    char* As, char* Bs, int* toks) {
  const int cnt = counts[e];
  if (m0 >= cnt) return;
  GEMM_VARS
  if (tid < BM) toks[tid] = lists[e * N + min(m0 + tid, cnt - 1)];
  __syncthreads();
  const size_t kofs = (size_t)ks * (H / 2) * 2;   // byte offset into K
  const char* gA0 = (const char*)hb + ((size_t)toks[sr0] * H) * 2 + kofs + scb;
  const char* gA1 = (const char*)hb + ((size_t)toks[sr1] * H) * 2 + kofs + scb;
  const char* gB0 = (const char*)w2b + ((size_t)e * C * H + (size_t)(c0 + sr0) * H) * 2 + kofs + scb;
  const char* gB1 = (const char*)w2b + ((size_t)e * C * H + (size_t)(c0 + sr1) * H) * 2 + kofs + scb;
  mfma_loop(gA0, gA1, gB0, gB1, As, Bs, wave, lane, (H / 2) / BK, mb, nb, acc);
  #pragma unroll
  for (int mi = 0; mi < 4; mi++) {
    #pragma unroll
    for (int r = 0; r < 4; r++) {
      int ml = mb + mi * 16 + quad * 4 + r;
      if (m0 + ml < cnt) {
        int tok = toks[ml] >> 1;
        float* orow = out + (size_t)tok * C + c0 + nb;
        #pragma unroll
        for (int ni = 0; ni < 4; ni++) atomicAdd(&orow[ni * 16 + col], acc[mi][ni][r]);
      }
    }
  }
}

__device__ __forceinline__ void run_vproj(
    const bf16* __restrict__ kkb, const bf16* __restrict__ vwb,
    const float* __restrict__ v_b, const float* __restrict__ sg,
    float* __restrict__ out, int n0, int c0, int ks, char* As, char* Bs) {
  GEMM_VARS
  const size_t kofs = (size_t)ks * (H / 2) * 2;
  const char* gA0 = (const char*)kkb + ((size_t)(n0 + sr0) * H) * 2 + kofs + scb;
  const char* gA1 = (const char*)kkb + ((size_t)(n0 + sr1) * H) * 2 + kofs + scb;
  const char* gB0 = (const char*)vwb + ((size_t)(c0 + sr0) * H) * 2 + kofs + scb;
  const char* gB1 = (const char*)vwb + ((size_t)(c0 + sr1) * H) * 2 + kofs + scb;
  mfma_loop(gA0, gA1, gB0, gB1, As, Bs, wave, lane, (H / 2) / BK, mb, nb, acc);
  #pragma unroll
  for (int mi = 0; mi < 4; mi++) {
    #pragma unroll
    for (int r = 0; r < 4; r++) {
      int n = n0 + mb + mi * 16 + quad * 4 + r;
      float sgv = sg[n];
      #pragma unroll
      for (int ni = 0; ni < 4; ni++) {
        int c = c0 + nb + ni * 16 + col;
        float add = sgv * acc[mi][ni][r];
        if (ks == 0) add += sgv * v_b[c];
        atomicAdd(&out[(size_t)n * C + c], add);
      }
    }
  }
}

// ==================================================================== PHASE 1
// bx [0,2048): up   [2048,2304): kproj   [2304,...): cvt w2+vw
__global__ __launch_bounds__(256) void phase1_kernel(
    const bf16* __restrict__ xtb, const bf16* __restrict__ w1b,
    const float* __restrict__ g, const int* __restrict__ lists,
    const int* __restrict__ counts, bf16* __restrict__ hb,
    const bf16* __restrict__ kwb, const float* __restrict__ rs2,
    const float* __restrict__ k_b, bf16* __restrict__ kkb,
    const float* __restrict__ w2, const float* __restrict__ vw,
    bf16* __restrict__ w2b, bf16* __restrict__ vwb) {
  __shared__ __align__(16) char As[BM * BK * 2];
  __shared__ __align__(16) char Bs[BN * BK * 2];
  __shared__ int toks[BM];
  const int bx = blockIdx.x;
  if (bx < P1_UP) {
    int e = bx >> 8, rem = bx & 255;
    int h0 = (rem & 15) * BN, m0 = (rem >> 4) * BM;
    run_up(xtb, w1b, g, lists, counts, hb, e, m0, h0, As, Bs, toks);
  } else if (bx < P1_UP + P1_KP) {
    int rem = bx - P1_UP;
    int n0 = (rem & 15) * BM, h0 = (rem >> 4) * BN;
    run_kproj(xtb, kwb, rs2, k_b, kkb, n0, h0, As, Bs);
  } else {
    cvt_pair(w2, w2b, (size_t)E * C * H / 4, vw, vwb, bx - P1_UP - P1_KP);
  }
}

// ==================================================================== PHASE 2
// bx [0,2048): down (split-K2)   [2048,2304): vproj (split-K2)
__global__ __launch_bounds__(256) void phase2_kernel(
    const bf16* __restrict__ hb, const bf16* __restrict__ w2b,
    const int* __restrict__ lists, const int* __restrict__ counts,
    const bf16* __restrict__ kkb, const bf16* __restrict__ vwb,
    const float* __restrict__ v_b, const float* __restrict__ sg,
    float* __restrict__ out) {
  __shared__ __align__(16) char As[BM * BK * 2];
  __shared__ __align__(16) char Bs[BN * BK * 2];
  __shared__ int toks[BM];
  const int bx = blockIdx.x;
  if (bx < P2_DOWN) {
    int z = bx >> 7, rem = bx & 127;
    int e = z >> 1, ks = z & 1;
    int c0 = (rem & 7) * BN, m0 = (rem >> 3) * BM;
    run_down(hb, w2b, lists, counts, out, e, ks, m0, c0, As, Bs, toks);
  } else {
    int rem = bx - P2_DOWN;
    int ks = rem >> 7, r2 = rem & 127;
    int n0 = (r2 & 15) * BM, c0 = (r2 >> 4) * BN;
    run_vproj(kkb, vwb, v_b, sg, out, n0, c0, ks, As, Bs);
  }
}

// -------------------------------------------------------------------- aux
// onehot column-mean is exactly 0.5*counts[e]/N
__global__ void aux_kernel(const float* __restrict__ scoresums,
                           const int* __restrict__ counts,
                           float* __restrict__ out_aux) {
  if (threadIdx.x == 0) {
    float a = 0.f;
    for (int e = 0; e < 8; e++)
      a += (0.5f * (float)counts[e] * (1.f / N)) * (scoresums[e] * (1.f / N));
    out_aux[0] = 8.f * a * 0.01f;
  }
}

extern "C" void kernel_launch(void* const* d_in, const int* in_sizes, int n_in,
                              void* d_out, int out_size, void* d_ws, size_t ws_size,
                              hipStream_t stream) {
  (void)in_sizes; (void)n_in; (void)ws_size;
  const float* x   = (const float*)d_in[0];
  const float* gw  = (const float*)d_in[1];
  const float* w1  = (const float*)d_in[2];
  const float* w2  = (const float*)d_in[3];
  const float* sgw = (const float*)d_in[4];
  const float* k_w = (const float*)d_in[5];
  const float* k_b = (const float*)d_in[6];
  const float* v_w = (const float*)d_in[7];
  const float* v_b = (const float*)d_in[8];
  float* out = (float*)d_out;

  // workspace layout (~100 MiB)
  char* p = (char*)d_ws;
  auto alloc = [&](size_t bytes) { char* r = p; p += (bytes + 255) & ~255ull; return r; };
  bf16* xtb  = (bf16*)alloc((size_t)N * C * 2);
  bf16* w1b  = (bf16*)alloc((size_t)E * H * C * 2);
  bf16* w2b  = (bf16*)alloc((size_t)E * C * H * 2);
  bf16* kwb  = (bf16*)alloc((size_t)H * C * 2);
  bf16* vwb  = (bf16*)alloc((size_t)C * H * 2);
  bf16* hb   = (bf16*)alloc((size_t)2 * N * H * 2);  // [2N][H], packed-slot rows
  bf16* kkb  = (bf16*)alloc((size_t)N * H * 2);      // separate: phase1 writes both
  float* rs2 = (float*)alloc((size_t)N * 4);
  float* g   = (float*)alloc((size_t)N * E * 4);
  float* sg  = (float*)alloc((size_t)N * 4);
  float* scoresums = (float*)alloc(256);             // +counts in next 256B slot
  int* counts = (int*)alloc(256);
  int* lists  = (int*)alloc((size_t)E * N * 4);

  hipMemsetAsync(d_out, 0, (size_t)out_size * sizeof(float), stream);
  hipMemsetAsync(scoresums, 0, 512, stream);         // covers scoresums + counts
  prep_kernel<<<PREP_TOTAL, 256, 0, stream>>>(
      x, gw, sgw, w1, k_w, xtb, rs2, g, sg, counts, lists, scoresums, w1b, kwb);
  phase1_kernel<<<P1_TOTAL, 256, 0, stream>>>(
      xtb, w1b, g, lists, counts, hb, kwb, rs2, k_b, kkb, w2, v_w, w2b, vwb);
  phase2_kernel<<<P2_TOTAL, 256, 0, stream>>>(
      hb, w2b, lists, counts, kkb, vwb, v_b, sg, out);
  aux_kernel<<<1, 64, 0, stream>>>(scoresums, counts, out + (size_t)N * C);
}